// Round 1
// 9260.563 us; speedup vs baseline: 1.0886x; 1.0886x over previous
//
#include <hip/hip_runtime.h>
#include <hip/hip_bf16.h>

#define BATCH 32
#define HID   512
#define EMB   512
#define VOCAB 50257
#define TSTEPS 64
#define JT2   64            // columns per logits block
#define G2    786           // ceil(VOCAB / JT2)

// ---------------------------------------------------------------------------
// k_init: x_curT[e][b] = emb[x[b]][e];  h0T/h1T[e][b] = h_prev[b][e]
// ---------------------------------------------------------------------------
__global__ __launch_bounds__(256) void k_init(const int* __restrict__ x,
                                              const float* __restrict__ h_prev,
                                              const float* __restrict__ emb,
                                              float* __restrict__ xT,
                                              float* __restrict__ h0T,
                                              float* __restrict__ h1T) {
    int b = blockIdx.x, tid = threadIdx.x;
    int tok = x[b];
    for (int e = tid; e < HID; e += 256) {
        xT[e * 32 + b] = emb[(size_t)tok * EMB + e];
        float hp = h_prev[b * HID + e];
        h0T[e * 32 + b] = hp;
        h1T[e * 32 + b] = hp;
    }
}

// ---------------------------------------------------------------------------
// k_small: outT = [tanh](inA @ WA [+ inB @ WB] + bias), feature-major in/out.
// grid 32 blocks x 256 thr. Block g owns 16 output cols; tid = ks*16+jl,
// ks in [0,16) slices K=512 into 32-wide chunks. acc[32] = all batch rows.
// Optionally also writes hout[b][t][j] (d_out h section).
// NOTE: part pad 257 is REQUIRED here (read lanes stride 257 → 2-way max).
// ---------------------------------------------------------------------------
__global__ __launch_bounds__(256) void k_small(const float* __restrict__ inA,
                                               const float* __restrict__ WA,
                                               const float* __restrict__ inB,
                                               const float* __restrict__ WB,
                                               const float* __restrict__ bias,
                                               float* __restrict__ outT,
                                               float* __restrict__ hout,
                                               int t, int do_tanh) {
    __shared__ float part[32 * 257];   // [b][tid], +1 pad → conflict-free
    int tid = threadIdx.x;
    int g = blockIdx.x;
    int j0 = g * 16;
    int jl = tid & 15, ks = tid >> 4;
    int k0 = ks * 32;
    int j = j0 + jl;

    float acc[32];
#pragma unroll
    for (int b = 0; b < 32; b++) acc[b] = 0.f;

    const float4* A4 = (const float4*)inA;
    if (inB != nullptr) {
        const float4* B4 = (const float4*)inB;
        for (int kk = 0; kk < 32; kk++) {
            int k = k0 + kk;
            float wa = WA[k * HID + j];
            float wb = WB[k * HID + j];
#pragma unroll
            for (int q = 0; q < 8; q++) {
                float4 a  = A4[k * 8 + q];
                float4 bv = B4[k * 8 + q];
                acc[q*4+0] = fmaf(a.x,  wa, acc[q*4+0]);
                acc[q*4+1] = fmaf(a.y,  wa, acc[q*4+1]);
                acc[q*4+2] = fmaf(a.z,  wa, acc[q*4+2]);
                acc[q*4+3] = fmaf(a.w,  wa, acc[q*4+3]);
                acc[q*4+0] = fmaf(bv.x, wb, acc[q*4+0]);
                acc[q*4+1] = fmaf(bv.y, wb, acc[q*4+1]);
                acc[q*4+2] = fmaf(bv.z, wb, acc[q*4+2]);
                acc[q*4+3] = fmaf(bv.w, wb, acc[q*4+3]);
            }
        }
    } else {
        for (int kk = 0; kk < 32; kk++) {
            int k = k0 + kk;
            float wa = WA[k * HID + j];
#pragma unroll
            for (int q = 0; q < 8; q++) {
                float4 a = A4[k * 8 + q];
                acc[q*4+0] = fmaf(a.x, wa, acc[q*4+0]);
                acc[q*4+1] = fmaf(a.y, wa, acc[q*4+1]);
                acc[q*4+2] = fmaf(a.z, wa, acc[q*4+2]);
                acc[q*4+3] = fmaf(a.w, wa, acc[q*4+3]);
            }
        }
    }

#pragma unroll
    for (int b = 0; b < 32; b++) part[b * 257 + tid] = acc[b];
    __syncthreads();

    // 512 outputs (16 j x 32 b), 2 per thread
#pragma unroll
    for (int i = 0; i < 2; i++) {
        int o = i * 256 + tid;
        int jlo = o >> 5, bo = o & 31;
        float s = 0.f;
#pragma unroll
        for (int k2 = 0; k2 < 16; k2++) s += part[bo * 257 + k2 * 16 + jlo];
        s += bias[j0 + jlo];
        if (do_tanh) s = tanhf(s);
        outT[(j0 + jlo) * 32 + bo] = s;
        if (hout != nullptr)
            hout[(size_t)bo * (TSTEPS * HID) + (size_t)t * HID + (j0 + jlo)] = s;
    }
}

// ---------------------------------------------------------------------------
// k_sm0: x1T = tanh(softmax_rows(z0T)), width 512. One block per batch row.
// ---------------------------------------------------------------------------
__global__ __launch_bounds__(256) void k_sm0(const float* __restrict__ z0T,
                                             float* __restrict__ x1T) {
    __shared__ float red[256];
    int b = blockIdx.x, tid = threadIdx.x;
    float v0 = z0T[tid * 32 + b];
    float v1 = z0T[(tid + 256) * 32 + b];
    red[tid] = fmaxf(v0, v1);
    __syncthreads();
    for (int s = 128; s > 0; s >>= 1) {
        if (tid < s) red[tid] = fmaxf(red[tid], red[tid + s]);
        __syncthreads();
    }
    float M = red[0];
    __syncthreads();
    float e0 = expf(v0 - M), e1 = expf(v1 - M);
    red[tid] = e0 + e1;
    __syncthreads();
    for (int s = 128; s > 0; s >>= 1) {
        if (tid < s) red[tid] += red[tid + s];
        __syncthreads();
    }
    float inv = 1.0f / red[0];
    x1T[tid * 32 + b]        = tanhf(e0 * inv);
    x1T[(tid + 256) * 32 + b] = tanhf(e1 * inv);
}

// ---------------------------------------------------------------------------
// k_z1: logits z1 = h1 @ V1 + c1 for step t (stored raw into d_out y-section),
// per-block per-row partial softmax stats (max, argmax, local expsum) to ws.
// Also (do_ywr) normalizes step t-1's y in place using M/Sinv from k_comb.
// grid 786 x 256. tid = ks*64 + jl; ks slices K=512 into 4 chunks of 128.
//
// OCCUPANCY IS THE POINT: LDS is exactly 32 KiB (no zrow, no pad — both
// partz access patterns are lane-consecutive, conflict-free at 256) and
// __launch_bounds__(256,4) caps VGPR ≤128 → 4 blocks/CU → 1024 co-resident
// ≥ 786 grid → single dispatch round (41 KiB LDS gave 3/CU → 768 < 786 →
// a serial 2nd round that ~doubled this kernel).
//
// k-loop unrolled ×8 with batched V1 loads → 8 outstanding VMEM per wave.
// Prior-step y normalization is split: loads issued at entry, exp/store
// after the matmul (HBM latency hidden under the FMA loop).
// ---------------------------------------------------------------------------
__global__ __launch_bounds__(256, 4) void k_z1(const float* __restrict__ h1T,
                                               const float* __restrict__ V1w,
                                               const float* __restrict__ c1,
                                               float* __restrict__ yout,
                                               float* __restrict__ pmax,
                                               float* __restrict__ psum,
                                               int* __restrict__ parg,
                                               const float* __restrict__ Mws,
                                               const float* __restrict__ Sinvws,
                                               int t, int do_ywr) {
    __shared__ float partz[32 * 256];
    int tid = threadIdx.x;
    int g = blockIdx.x;
    int j0 = g * JT2;
    int jl = tid & 63, ks = tid >> 6;
    int k0 = ks * 128;
    int jv = j0 + jl;
    int jc = jv < VOCAB ? jv : (VOCAB - 1);

    // ---- issue prior-step y loads early; finished after the matmul
    float yv[8];
    if (do_ywr) {
#pragma unroll
        for (int i = 0; i < 8; i++) {
            int o = i * 256 + tid;
            int bo = o >> 6;
            int jj = j0 + (o & 63);
            if (jj < VOCAB)
                yv[i] = yout[((size_t)bo * TSTEPS + (t - 1)) * VOCAB + jj];
        }
    }

    float acc[32];
#pragma unroll
    for (int b = 0; b < 32; b++) acc[b] = 0.f;

    const float4* h4 = (const float4*)h1T;
    const float*  vp = V1w + (size_t)k0 * VOCAB + jc;
    for (int kk = 0; kk < 128; kk += 8) {
        float v[8];
#pragma unroll
        for (int u = 0; u < 8; u++) v[u] = vp[(size_t)(kk + u) * VOCAB];
#pragma unroll
        for (int u = 0; u < 8; u++) {
            int kb = __builtin_amdgcn_readfirstlane(k0 + kk + u) * 8;
            float4 hq[4];
#pragma unroll
            for (int q = 0; q < 4; q++) hq[q] = h4[kb + q];
#pragma unroll
            for (int q = 0; q < 4; q++) {
                acc[q*4+0] = fmaf(hq[q].x, v[u], acc[q*4+0]);
                acc[q*4+1] = fmaf(hq[q].y, v[u], acc[q*4+1]);
                acc[q*4+2] = fmaf(hq[q].z, v[u], acc[q*4+2]);
                acc[q*4+3] = fmaf(hq[q].w, v[u], acc[q*4+3]);
            }
#pragma unroll
            for (int q = 0; q < 4; q++) hq[q] = h4[kb + 4 + q];
#pragma unroll
            for (int q = 0; q < 4; q++) {
                acc[16+q*4+0] = fmaf(hq[q].x, v[u], acc[16+q*4+0]);
                acc[16+q*4+1] = fmaf(hq[q].y, v[u], acc[16+q*4+1]);
                acc[16+q*4+2] = fmaf(hq[q].z, v[u], acc[16+q*4+2]);
                acc[16+q*4+3] = fmaf(hq[q].w, v[u], acc[16+q*4+3]);
            }
        }
    }

#pragma unroll
    for (int b = 0; b < 32; b++) partz[b * 256 + tid] = acc[b];

    // ---- finish y normalization for step t-1 (independent of the barrier)
    if (do_ywr) {
#pragma unroll
        for (int i = 0; i < 8; i++) {
            int o = i * 256 + tid;
            int bo = o >> 6;
            int jj = j0 + (o & 63);
            if (jj < VOCAB)
                yout[((size_t)bo * TSTEPS + (t - 1)) * VOCAB + jj]
                    = expf(yv[i] - Mws[bo]) * Sinvws[bo];
        }
    }
    __syncthreads();

    // ---- combine 4 K-slices, add bias, store raw logits; wave-butterfly
    // stats (max, first-argmax, expsum) — all 64 lanes of a wave hold one
    // row (bo = i*4 + wave), one column (jl) each.
    int w = tid >> 6;
#pragma unroll
    for (int i = 0; i < 8; i++) {
        int bo = i * 4 + w;
        float s = partz[bo * 256 + jl]
                + partz[bo * 256 + 64 + jl]
                + partz[bo * 256 + 128 + jl]
                + partz[bo * 256 + 192 + jl];
        int jj = j0 + jl;
        float z;
        if (jj < VOCAB) {
            z = s + c1[jj];
            yout[((size_t)bo * TSTEPS + t) * VOCAB + jj] = z;
        } else {
            z = -1e30f;   // pad lanes: never the max, exp → 0
        }
        // max + first-occurrence argmax across the 64 lanes
        float m = z; int a = jj;
#pragma unroll
        for (int d = 1; d < 64; d <<= 1) {
            float mo = __shfl_xor(m, d);
            int   ao = __shfl_xor(a, d);
            if (mo > m || (mo == m && ao < a)) { m = mo; a = ao; }
        }
        float e = expf(z - m);
        float ss = e;
#pragma unroll
        for (int d = 1; d < 64; d <<= 1) ss += __shfl_xor(ss, d);
        if (jl == 0) {
            pmax[bo * G2 + g] = m;
            psum[bo * G2 + g] = ss;
            parg[bo * G2 + g] = a;
        }
    }
}

// ---------------------------------------------------------------------------
// k_comb: per batch row, merge 786 block-partials → global M, Sinv, argmax
// (first-occurrence tie-break = min col among blocks achieving global max),
// then embed next token into x_curT. grid 32 x 256.
// ---------------------------------------------------------------------------
__global__ __launch_bounds__(256) void k_comb(const float* __restrict__ pmax,
                                              const float* __restrict__ psum,
                                              const int* __restrict__ parg,
                                              float* __restrict__ Mws,
                                              float* __restrict__ Sinvws,
                                              int* __restrict__ tokws,
                                              const float* __restrict__ emb,
                                              float* __restrict__ xT) {
    __shared__ float redm[256];
    __shared__ float reds[256];
    __shared__ int   redc[256];
    __shared__ int   toksh;
    int b = blockIdx.x, tid = threadIdx.x;

    float m = -1e30f;
    for (int g = tid; g < G2; g += 256) m = fmaxf(m, pmax[b * G2 + g]);
    redm[tid] = m;
    __syncthreads();
    for (int s = 128; s > 0; s >>= 1) {
        if (tid < s) redm[tid] = fmaxf(redm[tid], redm[tid + s]);
        __syncthreads();
    }
    float M = redm[0];

    float s_l = 0.f;
    int c_l = 0x7fffffff;
    for (int g = tid; g < G2; g += 256) {
        float pm = pmax[b * G2 + g];
        s_l += psum[b * G2 + g] * expf(pm - M);
        if (pm == M) c_l = min(c_l, parg[b * G2 + g]);
    }
    reds[tid] = s_l;
    redc[tid] = c_l;
    __syncthreads();
    for (int s = 128; s > 0; s >>= 1) {
        if (tid < s) {
            reds[tid] += reds[tid + s];
            redc[tid] = min(redc[tid], redc[tid + s]);
        }
        __syncthreads();
    }
    if (tid == 0) {
        Mws[b] = M;
        Sinvws[b] = 1.0f / reds[0];
        tokws[b] = redc[0];
        toksh = redc[0];
    }
    __syncthreads();
    int tok = toksh;
    for (int e = tid; e < HID; e += 256)
        xT[e * 32 + b] = emb[(size_t)tok * EMB + e];
}

// ---------------------------------------------------------------------------
// k_ywr: final normalize of step 63's y row (everything else is folded into
// the next step's k_z1).
// ---------------------------------------------------------------------------
__global__ __launch_bounds__(256) void k_ywr(float* __restrict__ yout,
                                             const float* __restrict__ Mws,
                                             const float* __restrict__ Sinvws) {
    int b = blockIdx.y;
    int v = blockIdx.x * 256 + threadIdx.x;
    if (v < VOCAB) {
        size_t idx = ((size_t)b * TSTEPS + (TSTEPS - 1)) * VOCAB + v;
        yout[idx] = expf(yout[idx] - Mws[b]) * Sinvws[b];
    }
}

// ---------------------------------------------------------------------------
extern "C" void kernel_launch(void* const* d_in, const int* in_sizes, int n_in,
                              void* d_out, int out_size, void* d_ws, size_t ws_size,
                              hipStream_t stream) {
    const int*   x      = (const int*)d_in[0];
    // d_in[1] = max_len (64), d_in[2] = eos_token_id — unused by reference math
    const float* h_prev = (const float*)d_in[3];
    const float* emb    = (const float*)d_in[4];
    const float* U0 = (const float*)d_in[5];
    const float* W0 = (const float*)d_in[6];
    const float* b0 = (const float*)d_in[7];
    const float* V0 = (const float*)d_in[8];
    const float* c0 = (const float*)d_in[9];
    const float* U1 = (const float*)d_in[10];
    const float* W1 = (const float*)d_in[11];
    const float* b1 = (const float*)d_in[12];
    const float* V1 = (const float*)d_in[13];
    const float* c1 = (const float*)d_in[14];

    float* out  = (float*)d_out;
    float* hout = out;                                   // (32, 64, 512)
    float* yout = out + (size_t)BATCH * TSTEPS * HID;    // (32, 64, 50257)

    // workspace carve (all 16B-aligned: every offset is a multiple of 32 floats)
    float* w = (float*)d_ws;
    float* xT    = w; w += HID * 32;
    float* h0Ta  = w; w += HID * 32;
    float* h0Tb  = w; w += HID * 32;
    float* h1Ta  = w; w += HID * 32;
    float* h1Tb  = w; w += HID * 32;
    float* z0T   = w; w += HID * 32;
    float* x1T   = w; w += HID * 32;
    float* pmax  = w; w += 32 * G2;
    float* psum  = w; w += 32 * G2;
    float* Mws   = w; w += 32;
    float* Sinvws= w; w += 32;
    int*   parg  = (int*)w; w += 32 * G2;
    int*   tokws = (int*)w; w += 32;

    hipLaunchKernelGGL(k_init, dim3(32), dim3(256), 0, stream,
                       x, h_prev, emb, xT, h0Ta, h1Ta);

    for (int t = 0; t < TSTEPS; t++) {
        float* h0p = (t & 1) ? h0Tb : h0Ta;
        float* h0n = (t & 1) ? h0Ta : h0Tb;
        float* h1p = (t & 1) ? h1Tb : h1Ta;
        float* h1n = (t & 1) ? h1Ta : h1Tb;

        // h0 = tanh(x @ U0 + h0_prev @ W0 + b0)
        hipLaunchKernelGGL(k_small, dim3(32), dim3(256), 0, stream,
                           xT, U0, h0p, W0, b0, h0n, (float*)nullptr, t, 1);
        // z0 = h0 @ V0 + c0
        hipLaunchKernelGGL(k_small, dim3(32), dim3(256), 0, stream,
                           h0n, V0, (const float*)nullptr, (const float*)nullptr,
                           c0, z0T, (float*)nullptr, t, 0);
        // x1 = tanh(softmax(z0))
        hipLaunchKernelGGL(k_sm0, dim3(32), dim3(256), 0, stream, z0T, x1T);
        // h1 = tanh(x1 @ U1 + h1_prev @ W1 + b1)   (also writes h output)
        hipLaunchKernelGGL(k_small, dim3(32), dim3(256), 0, stream,
                           x1T, U1, h1p, W1, b1, h1n, hout, t, 1);
        // z1 = h1 @ V1 + c1 (+ partial softmax stats; + normalize y of t-1)
        hipLaunchKernelGGL(k_z1, dim3(G2), dim3(256), 0, stream,
                           h1n, V1, c1, yout, pmax, psum, parg,
                           Mws, Sinvws, t, (t > 0) ? 1 : 0);
        // merge partials → M, Sinv, argmax; embed next token
        hipLaunchKernelGGL(k_comb, dim3(32), dim3(256), 0, stream,
                           pmax, psum, parg, Mws, Sinvws, tokws, emb, xT);
    }
    // normalize last step's y
    hipLaunchKernelGGL(k_ywr, dim3(dim3((VOCAB + 255) / 256, 32)), dim3(256), 0, stream,
                       yout, Mws, Sinvws);
}